// Round 22
// baseline (52.972 us; speedup 1.0000x reference)
//
#include <hip/hip_runtime.h>

#define NPTS 262144
#define HID  20
#define NMID 8

typedef float f32x16 __attribute__((ext_vector_type(16)));
typedef float f32x2 __attribute__((ext_vector_type(2)));
typedef _Float16 half8 __attribute__((ext_vector_type(8)));
typedef __fp16 fp16x2 __attribute__((ext_vector_type(2)));
typedef unsigned int u32;

// RTZ fp16 pair pack (1 op, v_cvt_pkrtz_f16_f32) — all fragment packs.
__device__ __forceinline__ u32 pkh_rtz(float a, float b) {
    fp16x2 r = __builtin_amdgcn_cvt_pkrtz(a, b);
    return __builtin_bit_cast(u32, r);
}
__device__ __forceinline__ u32 pkh2(f32x2 v) { return pkh_rtz(v.x, v.y); }

__device__ __forceinline__ half8 mk_fragh(u32 a, u32 b, u32 c, u32 d) {
    uint4 v = make_uint4(a, b, c, d);
    return __builtin_bit_cast(half8, v);
}

#define MF2(A, Bo, C) __builtin_amdgcn_mfma_f32_32x32x16_f16(A, Bo, C, 0, 0, 0)

__launch_bounds__(256, 4)
__global__ void pde_mfma_kernel(const float* __restrict__ x,
                                const float* __restrict__ W_in,
                                const float* __restrict__ b_in,
                                const float* __restrict__ W_mid,
                                const float* __restrict__ b_mid,
                                const float* __restrict__ W_out,
                                const float* __restrict__ b_out,
                                float* __restrict__ out) {
    // fp16 A-frags, 3 parts/layer (24 KB): part0 = hi s=0; part1 = merged s=1
    // (lanes 0..31 hi, 32..63 lo); part2 = lo s=0. Lanes>=32 read s=1 frags from
    // a zero block (their A rows are zero). Weight k-columns permuted
    // (k -> k^12 for k in [4,12)) so B-frags equal local C/D register order.
    // H stream: hi+lo fp16 weights (21-bit eff). T/X/Q: hi only (11-bit).
    __shared__ short sWf[NMID * 3 * 64 * 8];   // 24 KB
    __shared__ float sIn[2 * 16 * 4];
    __shared__ short sZero[8];

    const int tid = threadIdx.x;

    for (int idx = tid; idx < NMID * 3 * 64 * 8 / 2; idx += 256)
        ((u32*)sWf)[idx] = 0u;
    if (tid < 4) ((u32*)sZero)[tid] = 0u;
    for (int idx = tid; idx < 32; idx += 256) {
        int hh = idx >> 4, reg = idx & 15;
        int n = (reg & 3) + 8 * (reg >> 2) + 4 * hh;
        float w0 = 0.f, w1 = 0.f, b = 0.f, wo = 0.f;
        if (n < HID) { w0 = W_in[n * 2]; w1 = W_in[n * 2 + 1]; b = b_in[n]; wo = W_out[n]; }
        sIn[idx * 4 + 0] = w0; sIn[idx * 4 + 1] = w1;
        sIn[idx * 4 + 2] = b;  sIn[idx * 4 + 3] = wo;
    }
    __syncthreads();
    // staging: per-layer outer loop -> only a divmod by 21 per element.
    for (int layer = 0; layer < NMID; ++layer) {
        const float* Wl = W_mid + layer * HID * HID;
        const float* bl = b_mid + layer * HID;
        for (int e = tid; e < HID * (HID + 1); e += 256) {
            int j = e / (HID + 1);
            int k = e - j * (HID + 1);
            float w = (k < HID) ? Wl[j * HID + k] : bl[j];
            _Float16 whf = (_Float16)w;                       // RNE
            _Float16 wlf = (_Float16)(w - (float)whf);        // exact residual
            short whib = (short)__builtin_bit_cast(unsigned short, whf);
            short wlob = (short)__builtin_bit_cast(unsigned short, wlf);
            int kp = (k >= 4 && k < 12) ? (k ^ 12) : k;   // column permutation
            int s = kp >> 4, kk = kp & 15, hh = kk >> 3, r = kk & 7;
            int lane = j + 32 * hh;
            if (s == 0) {
                sWf[((layer * 3 + 0) * 64 + lane) * 8 + r] = whib;   // hi s0
                sWf[((layer * 3 + 2) * 64 + lane) * 8 + r] = wlob;   // lo s0
            } else {
                sWf[((layer * 3 + 1) * 64 + lane) * 8 + r]      = whib;  // hi s1
                sWf[((layer * 3 + 1) * 64 + lane + 32) * 8 + r] = wlob;  // lo s1
            }
        }
    }
    __syncthreads();

    const int lane = tid & 63;
    const int wv   = tid >> 6;
    const int p    = lane & 31;
    const int hi   = lane >> 5;
    const int P    = blockIdx.x * 128 + wv * 32 + p;

    const float2 xv = reinterpret_cast<const float2*>(x)[P];
    const float x0 = xv.x, x1 = xv.y;
    const float bo = b_out[0];

    const float4* sIn4 = reinterpret_cast<const float4*>(sIn);

    // f32x2 state pairs — pk-f32 pointwise, same precision as scalars.
    f32x2 vh[6], vs[6], vt[6], vx[6], vq[6];

    // ---- input layer (fp32, exact) ----
    #pragma unroll
    for (int rr = 0; rr < 6; ++rr) {
        #pragma unroll
        for (int j2 = 0; j2 < 2; ++j2) {
            float4 tt = sIn4[hi * 16 + 2 * rr + j2];
            float z = fmaf(tt.x, x0, fmaf(tt.y, x1, tt.z));
            float e = __expf(z + z);
            float rc = __fdividef(1.0f, e + 1.0f);
            float a = fmaf(-2.0f, rc, 1.0f);
            float s = fmaf(-a, a, 1.0f);
            float sx = s * tt.y;
            vh[rr][j2] = a; vs[rr][j2] = s; vt[rr][j2] = s * tt.x;
            vx[rr][j2] = sx; vq[rr][j2] = -2.0f * a * sx * tt.y;
        }
    }

    const f32x16 zz = 0.0f;
    const half8* afp = reinterpret_cast<const half8*>(sWf);
    const half8* pz  = reinterpret_cast<const half8*>(sZero);

    const half8* s1h = (lane < 32) ? (afp + 64 + lane)      : pz;
    const half8* s1l = (lane < 32) ? (afp + 64 + 32 + lane) : pz;
    const int s1stride = (lane < 32) ? 192 : 0;

    for (int layer = 0; layer < NMID; ++layer) {
        const int base = layer * 3 * 64;
        const half8 wh0 = afp[base + lane];
        const half8 wl0 = afp[base + 128 + lane];
        const half8 wh1 = s1h[layer * s1stride];
        const half8 wl1 = s1l[layer * s1stride];

        // ---- phase 1: fragments (1-op RTZ packs) + H MFMAs (aH live: 16) ----
        const half8 bH0 = mk_fragh(pkh2(vh[0]), pkh2(vh[1]), pkh2(vh[2]), pkh2(vh[3]));
        const half8 bH1 = mk_fragh(pkh2(vh[4]), pkh2(vh[5]), 0x00003C00u, 0u);
        const half8 bT0 = mk_fragh(pkh2(vt[0]), pkh2(vt[1]), pkh2(vt[2]), pkh2(vt[3]));
        const half8 bT1 = mk_fragh(pkh2(vt[4]), pkh2(vt[5]), 0u, 0u);
        f32x16 aH = MF2(wh0, bH0, zz);
        aH = MF2(wh1, bH1, aH);
        aH = MF2(wl0, bH0, aH);
        aH = MF2(wl1, bH1, aH);

        // ---- phase 2: tanh (scalar f32) -> a; s via pk-fma ----
        #pragma unroll
        for (int rr = 0; rr < 6; ++rr) {
            #pragma unroll
            for (int j2 = 0; j2 < 2; ++j2) {
                float z = aH[2 * rr + j2];
                float e = __expf(z + z);
                float rc = __fdividef(1.0f, e + 1.0f);
                vh[rr][j2] = fmaf(-2.0f, rc, 1.0f);
            }
            vs[rr] = -(vh[rr] * vh[rr]) + 1.0f;   // v_pk_fma_f32
        }
        __builtin_amdgcn_sched_barrier(0);

        // ---- phase 3: T MFMAs + pk-f32 update (aT live: 16) ----
        f32x16 aT = MF2(wh0, bT0, zz);
        aT = MF2(wh1, bT1, aT);
        #pragma unroll
        for (int rr = 0; rr < 6; ++rr) {
            f32x2 zt; zt.x = aT[2 * rr]; zt.y = aT[2 * rr + 1];
            vt[rr] = vs[rr] * zt;                 // v_pk_mul_f32
        }

        const half8 bX0 = mk_fragh(pkh2(vx[0]), pkh2(vx[1]), pkh2(vx[2]), pkh2(vx[3]));
        const half8 bX1 = mk_fragh(pkh2(vx[4]), pkh2(vx[5]), 0u, 0u);
        const half8 bQ0 = mk_fragh(pkh2(vq[0]), pkh2(vq[1]), pkh2(vq[2]), pkh2(vq[3]));
        const half8 bQ1 = mk_fragh(pkh2(vq[4]), pkh2(vq[5]), 0u, 0u);
        __builtin_amdgcn_sched_barrier(0);

        // ---- phase 4a: X MFMAs, consume into vx and w (aX live: 16) ----
        f32x16 aX = MF2(wh0, bX0, zz);
        aX = MF2(wh1, bX1, aX);
        f32x2 w6[6];
        #pragma unroll
        for (int rr = 0; rr < 6; ++rr) {
            f32x2 zx; zx.x = aX[2 * rr]; zx.y = aX[2 * rr + 1];
            f32x2 nx = vs[rr] * zx;               // pk_mul
            f32x2 u  = vh[rr] * nx;               // pk_mul
            f32x2 t2 = u + u;                     // pk_add
            vx[rr] = nx;
            w6[rr] = t2 * zx;                     // pk_mul
        }
        __builtin_amdgcn_sched_barrier(0);

        // ---- phase 4b: Q MFMAs, consume (aQ live: 16 — peak acc now 16) ----
        f32x16 aQ = MF2(wh0, bQ0, zz);
        aQ = MF2(wh1, bQ1, aQ);
        #pragma unroll
        for (int rr = 0; rr < 6; ++rr) {
            f32x2 zq; zq.x = aQ[2 * rr]; zq.y = aQ[2 * rr + 1];
            vq[rr] = vs[rr] * zq - w6[rr];        // pk_fma
        }
    }

    // ---- output layer ----
    float f = 0.f, ft = 0.f, fx = 0.f, fxx = 0.f;
    #pragma unroll
    for (int rr = 0; rr < 6; ++rr) {
        #pragma unroll
        for (int j2 = 0; j2 < 2; ++j2) {
            float w = sIn4[hi * 16 + 2 * rr + j2].w;
            f   = fmaf(w, vh[rr][j2], f);
            ft  = fmaf(w, vt[rr][j2], ft);
            fx  = fmaf(w, vx[rr][j2], fx);
            fxx = fmaf(w, vq[rr][j2], fxx);
        }
    }
    f   += __shfl_xor(f, 32);
    ft  += __shfl_xor(ft, 32);
    fx  += __shfl_xor(fx, 32);
    fxx += __shfl_xor(fxx, 32);
    f += bo;

    if (!hi) {
        const float pde = 0.5f * x1 * x1 + ft + 0.5f * fxx + 0.5f * x1 * fx
                          - 0.069444444444444f * fx * fx;
        out[P] = f;
        out[NPTS + P] = pde;
    }
}

extern "C" void kernel_launch(void* const* d_in, const int* in_sizes, int n_in,
                              void* d_out, int out_size, void* d_ws, size_t ws_size,
                              hipStream_t stream) {
    const float* x     = (const float*)d_in[0];
    const float* W_in  = (const float*)d_in[1];
    const float* b_in  = (const float*)d_in[2];
    const float* W_mid = (const float*)d_in[3];
    const float* b_mid = (const float*)d_in[4];
    const float* W_out = (const float*)d_in[5];
    const float* b_out = (const float*)d_in[6];
    float* out = (float*)d_out;

    hipLaunchKernelGGL(pde_mfma_kernel, dim3(NPTS / 128), dim3(256), 0, stream,
                       x, W_in, b_in, W_mid, b_mid, W_out, b_out, out);
}

// Round 23
// 52.664 us; speedup vs baseline: 1.0059x; 1.0059x over previous
//
#include <hip/hip_runtime.h>

#define NPTS 262144
#define HID  20
#define NMID 8

typedef float f32x16 __attribute__((ext_vector_type(16)));
typedef _Float16 half8 __attribute__((ext_vector_type(8)));
typedef _Float16 half2v __attribute__((ext_vector_type(2)));
typedef __fp16 fp16x2 __attribute__((ext_vector_type(2)));
typedef unsigned int u32;

// RNE fp16 pair pack (2 cvt + pack) — value (H) stream.
__device__ __forceinline__ u32 pkh_rne(float a, float b) {
    half2v r; r.x = (_Float16)a; r.y = (_Float16)b;
    return __builtin_bit_cast(u32, r);
}
// RTZ fp16 pair pack (1 op, v_cvt_pkrtz_f16_f32) — derivative streams.
__device__ __forceinline__ u32 pkh_rtz(float a, float b) {
    fp16x2 r = __builtin_amdgcn_cvt_pkrtz(a, b);
    return __builtin_bit_cast(u32, r);
}

__device__ __forceinline__ half8 mk_fragh(u32 a, u32 b, u32 c, u32 d) {
    uint4 v = make_uint4(a, b, c, d);
    return __builtin_bit_cast(half8, v);
}

#define MF2(A, B, C) __builtin_amdgcn_mfma_f32_32x32x16_f16(A, B, C, 0, 0, 0)

__global__ void pde_mfma_kernel(const float* __restrict__ x,
                                const float* __restrict__ W_in,
                                const float* __restrict__ b_in,
                                const float* __restrict__ W_mid,
                                const float* __restrict__ b_mid,
                                const float* __restrict__ W_out,
                                const float* __restrict__ b_out,
                                float* __restrict__ out) {
    // fp16 A-frags, 3 parts/layer (24 KB): part0 = hi s=0; part1 = merged s=1
    // (lanes 0..31 hi, 32..63 lo); part2 = lo s=0. Lanes>=32 read s=1 frags from
    // a zero block (their A rows are zero). Weight k-columns permuted
    // (k -> k^12 for k in [4,12)) so B-frags equal local C/D register order.
    // H stream: hi+lo fp16 weights (21-bit eff). T/X/Q: hi only (11-bit).
    // NO __launch_bounds__: let the compiler use a big VGPR budget so MFMA
    // accumulators stay in VGPR form (no v_accvgpr_* shuffle) [R22 theory].
    __shared__ short sWf[NMID * 3 * 64 * 8];   // 24 KB
    __shared__ float sIn[2 * 16 * 4];
    __shared__ short sZero[8];

    const int tid = threadIdx.x;

    for (int idx = tid; idx < NMID * 3 * 64 * 8 / 2; idx += 256)
        ((u32*)sWf)[idx] = 0u;
    if (tid < 4) ((u32*)sZero)[tid] = 0u;
    for (int idx = tid; idx < 32; idx += 256) {
        int h2i = idx >> 4, reg = idx & 15;
        int n = (reg & 3) + 8 * (reg >> 2) + 4 * h2i;
        float w0 = 0.f, w1 = 0.f, b = 0.f, wo = 0.f;
        if (n < HID) { w0 = W_in[n * 2]; w1 = W_in[n * 2 + 1]; b = b_in[n]; wo = W_out[n]; }
        sIn[idx * 4 + 0] = w0; sIn[idx * 4 + 1] = w1;
        sIn[idx * 4 + 2] = b;  sIn[idx * 4 + 3] = wo;
    }
    __syncthreads();
    // staging: per-layer outer loop -> only a divmod by 21 per element.
    for (int layer = 0; layer < NMID; ++layer) {
        const float* Wl = W_mid + layer * HID * HID;
        const float* bl = b_mid + layer * HID;
        for (int e = tid; e < HID * (HID + 1); e += 256) {
            int j = e / (HID + 1);
            int k = e - j * (HID + 1);
            float w = (k < HID) ? Wl[j * HID + k] : bl[j];
            _Float16 whf = (_Float16)w;                       // RNE
            _Float16 wlf = (_Float16)(w - (float)whf);        // exact residual
            short whib = (short)__builtin_bit_cast(unsigned short, whf);
            short wlob = (short)__builtin_bit_cast(unsigned short, wlf);
            int kp = (k >= 4 && k < 12) ? (k ^ 12) : k;   // column permutation
            int s = kp >> 4, kk = kp & 15, hh = kk >> 3, r = kk & 7;
            int lane = j + 32 * hh;
            if (s == 0) {
                sWf[((layer * 3 + 0) * 64 + lane) * 8 + r] = whib;   // hi s0
                sWf[((layer * 3 + 2) * 64 + lane) * 8 + r] = wlob;   // lo s0
            } else {
                sWf[((layer * 3 + 1) * 64 + lane) * 8 + r]      = whib;  // hi s1
                sWf[((layer * 3 + 1) * 64 + lane + 32) * 8 + r] = wlob;  // lo s1
            }
        }
    }
    __syncthreads();

    const int lane = tid & 63;
    const int wv   = tid >> 6;
    const int p    = lane & 31;
    const int hi   = lane >> 5;
    const int P    = blockIdx.x * 128 + wv * 32 + p;

    const float2 xv = reinterpret_cast<const float2*>(x)[P];
    const float x0 = xv.x, x1 = xv.y;
    const float bo = b_out[0];

    const float4* sIn4 = reinterpret_cast<const float4*>(sIn);

    float vh[12], vs[12], vt[12], vx[12], vxx[12];

    // ---- input layer (fp32, exact) ----
    #pragma unroll
    for (int r = 0; r < 12; ++r) {
        float4 t = sIn4[hi * 16 + r];
        float z = fmaf(t.x, x0, fmaf(t.y, x1, t.z));
        float e = __expf(z + z);
        float rc = __fdividef(1.0f, e + 1.0f);
        float a = fmaf(-2.0f, rc, 1.0f);
        float s = fmaf(-a, a, 1.0f);
        float sx = s * t.y;
        vh[r] = a; vt[r] = s * t.x; vx[r] = sx;
        vxx[r] = -2.0f * a * sx * t.y;
    }

    const f32x16 zz = 0.0f;
    const half8* afp = reinterpret_cast<const half8*>(sWf);
    const half8* pz  = reinterpret_cast<const half8*>(sZero);

    const half8* s1h = (lane < 32) ? (afp + 64 + lane)      : pz;
    const half8* s1l = (lane < 32) ? (afp + 64 + 32 + lane) : pz;
    const int s1stride = (lane < 32) ? 192 : 0;

    for (int layer = 0; layer < NMID; ++layer) {
        const int base = layer * 3 * 64;
        const half8 wh0 = afp[base + lane];
        const half8 wl0 = afp[base + 128 + lane];
        const half8 wh1 = s1h[layer * s1stride];
        const half8 wl1 = s1l[layer * s1stride];

        // ---- phase 1: H fragments (fp16 RNE) + 4 H MFMAs (hi+lo weights) ----
        const half8 bH0 = mk_fragh(pkh_rne(vh[0], vh[1]), pkh_rne(vh[2], vh[3]),
                                   pkh_rne(vh[4], vh[5]), pkh_rne(vh[6], vh[7]));
        const half8 bH1 = mk_fragh(pkh_rne(vh[8], vh[9]), pkh_rne(vh[10], vh[11]),
                                   0x00003C00u, 0u);      // bias col k=20 = 1.0 fp16
        f32x16 aH = MF2(wh0, bH0, zz);
        aH = MF2(wh1, bH1, aH);
        aH = MF2(wl0, bH0, aH);
        aH = MF2(wl1, bH1, aH);

        // pack T early (from previous-layer vt; independent of aH)
        const half8 bT0 = mk_fragh(pkh_rtz(vt[0], vt[1]), pkh_rtz(vt[2], vt[3]),
                                   pkh_rtz(vt[4], vt[5]), pkh_rtz(vt[6], vt[7]));
        const half8 bT1 = mk_fragh(pkh_rtz(vt[8], vt[9]), pkh_rtz(vt[10], vt[11]),
                                   0u, 0u);

        // ---- phase 2: tanh (consumes aH) ----
        #pragma unroll
        for (int r = 0; r < 12; ++r) {
            float z = aH[r];
            float e = __expf(z + z);
            float rc = __fdividef(1.0f, e + 1.0f);
            float a = fmaf(-2.0f, rc, 1.0f);
            vh[r] = a; vs[r] = fmaf(-a, a, 1.0f);
        }
        __builtin_amdgcn_sched_barrier(0);   // keep T MFMAs below aH consumption

        // ---- phase 3: T MFMAs (hi weights only) + consume ----
        f32x16 aT = MF2(wh0, bT0, zz);
        aT = MF2(wh1, bT1, aT);
        #pragma unroll
        for (int r = 0; r < 12; ++r) vt[r] = vs[r] * aT[r];

        // pack X/Q (from previous-layer vx, vxx)
        const half8 bX0 = mk_fragh(pkh_rtz(vx[0], vx[1]), pkh_rtz(vx[2], vx[3]),
                                   pkh_rtz(vx[4], vx[5]), pkh_rtz(vx[6], vx[7]));
        const half8 bX1 = mk_fragh(pkh_rtz(vx[8], vx[9]), pkh_rtz(vx[10], vx[11]),
                                   0u, 0u);
        const half8 bQ0 = mk_fragh(pkh_rtz(vxx[0], vxx[1]), pkh_rtz(vxx[2], vxx[3]),
                                   pkh_rtz(vxx[4], vxx[5]), pkh_rtz(vxx[6], vxx[7]));
        const half8 bQ1 = mk_fragh(pkh_rtz(vxx[8], vxx[9]), pkh_rtz(vxx[10], vxx[11]),
                                   0u, 0u);
        __builtin_amdgcn_sched_barrier(0);   // keep X/Q MFMAs below aT consumption

        // ---- phase 4: X and Q MFMAs (hi weights only) + pointwise ----
        f32x16 aX = MF2(wh0, bX0, zz);   f32x16 aQ = MF2(wh0, bQ0, zz);
        aX = MF2(wh1, bX1, aX);          aQ = MF2(wh1, bQ1, aQ);

        #pragma unroll
        for (int r = 0; r < 12; ++r) {
            float zx = aX[r];
            float a = vh[r], s = vs[r];
            float nx = s * zx;
            float t2 = 2.0f * a * nx;
            vx[r] = nx;
            vxx[r] = fmaf(-t2, zx, s * aQ[r]);
        }
    }

    // ---- output layer ----
    float f = 0.f, ft = 0.f, fx = 0.f, fxx = 0.f;
    #pragma unroll
    for (int r = 0; r < 12; ++r) {
        float4 t = sIn4[hi * 16 + r];
        f   = fmaf(t.w, vh[r],  f);
        ft  = fmaf(t.w, vt[r],  ft);
        fx  = fmaf(t.w, vx[r],  fx);
        fxx = fmaf(t.w, vxx[r], fxx);
    }
    f   += __shfl_xor(f, 32);
    ft  += __shfl_xor(ft, 32);
    fx  += __shfl_xor(fx, 32);
    fxx += __shfl_xor(fxx, 32);
    f += bo;

    if (!hi) {
        const float pde = 0.5f * x1 * x1 + ft + 0.5f * fxx + 0.5f * x1 * fx
                          - 0.069444444444444f * fx * fx;
        out[P] = f;
        out[NPTS + P] = pde;
    }
}

extern "C" void kernel_launch(void* const* d_in, const int* in_sizes, int n_in,
                              void* d_out, int out_size, void* d_ws, size_t ws_size,
                              hipStream_t stream) {
    const float* x     = (const float*)d_in[0];
    const float* W_in  = (const float*)d_in[1];
    const float* b_in  = (const float*)d_in[2];
    const float* W_mid = (const float*)d_in[3];
    const float* b_mid = (const float*)d_in[4];
    const float* W_out = (const float*)d_in[5];
    const float* b_out = (const float*)d_in[6];
    float* out = (float*)d_out;

    hipLaunchKernelGGL(pde_mfma_kernel, dim3(NPTS / 128), dim3(256), 0, stream,
                       x, W_in, b_in, W_mid, b_mid, W_out, b_out, out);
}

// Round 24
// 50.175 us; speedup vs baseline: 1.0557x; 1.0496x over previous
//
#include <hip/hip_runtime.h>

#define NPTS 262144
#define HID  20
#define NMID 8

typedef float f32x16 __attribute__((ext_vector_type(16)));
typedef _Float16 half8 __attribute__((ext_vector_type(8)));
typedef _Float16 half2v __attribute__((ext_vector_type(2)));
typedef __fp16 fp16x2 __attribute__((ext_vector_type(2)));
typedef unsigned int u32;

// RNE fp16 pair pack — value (H) stream (unbiased rounding for the value path).
__device__ __forceinline__ u32 pkh_rne(float a, float b) {
    half2v r; r.x = (_Float16)a; r.y = (_Float16)b;
    return __builtin_bit_cast(u32, r);
}
// RTZ fp16 pair pack (1 op, v_cvt_pkrtz_f16_f32) — derivative streams.
__device__ __forceinline__ u32 pkh_rtz(float a, float b) {
    fp16x2 r = __builtin_amdgcn_cvt_pkrtz(a, b);
    return __builtin_bit_cast(u32, r);
}

__device__ __forceinline__ half8 mk_fragh(u32 a, u32 b, u32 c, u32 d) {
    uint4 v = make_uint4(a, b, c, d);
    return __builtin_bit_cast(half8, v);
}

#define MF2(A, B, C) __builtin_amdgcn_mfma_f32_32x32x16_f16(A, B, C, 0, 0, 0)

__launch_bounds__(256, 4)
__global__ void pde_mfma_kernel(const float* __restrict__ x,
                                const float* __restrict__ W_in,
                                const float* __restrict__ b_in,
                                const float* __restrict__ W_mid,
                                const float* __restrict__ b_mid,
                                const float* __restrict__ W_out,
                                const float* __restrict__ b_out,
                                float* __restrict__ out) {
    // fp16 A-frags, hi-only weights, 2 parts/layer (16.4 KB):
    //   part0 = s=0 (64 lanes), part1 = s=1 (only lanes 0..19 nonzero; lanes
    //   32..63 correspond to k=24..31 — zero columns — so NO zero-block
    //   redirect is needed; zero-filled LDS supplies the zeros).
    // Weight k-columns permuted (k -> k^12 for k in [4,12)) so B-frags equal
    // local C/D register order for both lane halves — no cross-lane ops.
    __shared__ short sWf[NMID * 2 * 64 * 8];   // 16 KB
    __shared__ float sIn[2 * 16 * 4];

    const int tid = threadIdx.x;

    for (int idx = tid; idx < NMID * 2 * 64 * 8 / 2; idx += 256)
        ((u32*)sWf)[idx] = 0u;
    for (int idx = tid; idx < 32; idx += 256) {
        int h2i = idx >> 4, reg = idx & 15;
        int n = (reg & 3) + 8 * (reg >> 2) + 4 * h2i;
        float w0 = 0.f, w1 = 0.f, b = 0.f, wo = 0.f;
        if (n < HID) { w0 = W_in[n * 2]; w1 = W_in[n * 2 + 1]; b = b_in[n]; wo = W_out[n]; }
        sIn[idx * 4 + 0] = w0; sIn[idx * 4 + 1] = w1;
        sIn[idx * 4 + 2] = b;  sIn[idx * 4 + 3] = wo;
    }
    __syncthreads();
    // staging: per-layer outer loop -> divmod by 21 only; hi fp16 only.
    for (int layer = 0; layer < NMID; ++layer) {
        const float* Wl = W_mid + layer * HID * HID;
        const float* bl = b_mid + layer * HID;
        for (int e = tid; e < HID * (HID + 1); e += 256) {
            int j = e / (HID + 1);
            int k = e - j * (HID + 1);
            float w = (k < HID) ? Wl[j * HID + k] : bl[j];
            _Float16 whf = (_Float16)w;                       // RNE
            short whib = (short)__builtin_bit_cast(unsigned short, whf);
            int kp = (k >= 4 && k < 12) ? (k ^ 12) : k;   // column permutation
            int s = kp >> 4, kk = kp & 15, hh = kk >> 3, r = kk & 7;
            int lane = j + 32 * hh;
            sWf[((layer * 2 + s) * 64 + lane) * 8 + r] = whib;
        }
    }
    __syncthreads();

    const int lane = tid & 63;
    const int wv   = tid >> 6;
    const int p    = lane & 31;
    const int hi   = lane >> 5;
    const int P    = blockIdx.x * 128 + wv * 32 + p;

    const float2 xv = reinterpret_cast<const float2*>(x)[P];
    const float x0 = xv.x, x1 = xv.y;
    const float bo = b_out[0];

    const float4* sIn4 = reinterpret_cast<const float4*>(sIn);

    float vh[12], vs[12], vt[12], vx[12], vxx[12];

    // ---- input layer (fp32, exact) ----
    #pragma unroll
    for (int r = 0; r < 12; ++r) {
        float4 t = sIn4[hi * 16 + r];
        float z = fmaf(t.x, x0, fmaf(t.y, x1, t.z));
        float e = __expf(z + z);
        float rc = __fdividef(1.0f, e + 1.0f);
        float a = fmaf(-2.0f, rc, 1.0f);
        float s = fmaf(-a, a, 1.0f);
        float sx = s * t.y;
        vh[r] = a; vt[r] = s * t.x; vx[r] = sx;
        vxx[r] = -2.0f * a * sx * t.y;
    }

    const f32x16 zz = 0.0f;
    const half8* afp = reinterpret_cast<const half8*>(sWf);

    for (int layer = 0; layer < NMID; ++layer) {
        const int base = layer * 2 * 64;
        const half8 wh0 = afp[base + lane];
        const half8 wh1 = afp[base + 64 + lane];

        // ---- phase 1: H fragments (fp16 RNE) + 2 H MFMAs ----
        const half8 bH0 = mk_fragh(pkh_rne(vh[0], vh[1]), pkh_rne(vh[2], vh[3]),
                                   pkh_rne(vh[4], vh[5]), pkh_rne(vh[6], vh[7]));
        const half8 bH1 = mk_fragh(pkh_rne(vh[8], vh[9]), pkh_rne(vh[10], vh[11]),
                                   0x00003C00u, 0u);      // bias col k=20 = 1.0 fp16
        f32x16 aH = MF2(wh0, bH0, zz);
        aH = MF2(wh1, bH1, aH);

        // pack T early (from previous-layer vt; independent of aH)
        const half8 bT0 = mk_fragh(pkh_rtz(vt[0], vt[1]), pkh_rtz(vt[2], vt[3]),
                                   pkh_rtz(vt[4], vt[5]), pkh_rtz(vt[6], vt[7]));
        const half8 bT1 = mk_fragh(pkh_rtz(vt[8], vt[9]), pkh_rtz(vt[10], vt[11]),
                                   0u, 0u);

        // ---- phase 2: tanh (consumes aH) ----
        #pragma unroll
        for (int r = 0; r < 12; ++r) {
            float z = aH[r];
            float e = __expf(z + z);
            float rc = __fdividef(1.0f, e + 1.0f);
            float a = fmaf(-2.0f, rc, 1.0f);
            vh[r] = a; vs[r] = fmaf(-a, a, 1.0f);
        }
        __builtin_amdgcn_sched_barrier(0);   // keep T MFMAs below aH consumption

        // ---- phase 3: T MFMAs + consume ----
        f32x16 aT = MF2(wh0, bT0, zz);
        aT = MF2(wh1, bT1, aT);
        #pragma unroll
        for (int r = 0; r < 12; ++r) vt[r] = vs[r] * aT[r];

        // pack X/Q (from previous-layer vx, vxx)
        const half8 bX0 = mk_fragh(pkh_rtz(vx[0], vx[1]), pkh_rtz(vx[2], vx[3]),
                                   pkh_rtz(vx[4], vx[5]), pkh_rtz(vx[6], vx[7]));
        const half8 bX1 = mk_fragh(pkh_rtz(vx[8], vx[9]), pkh_rtz(vx[10], vx[11]),
                                   0u, 0u);
        const half8 bQ0 = mk_fragh(pkh_rtz(vxx[0], vxx[1]), pkh_rtz(vxx[2], vxx[3]),
                                   pkh_rtz(vxx[4], vxx[5]), pkh_rtz(vxx[6], vxx[7]));
        const half8 bQ1 = mk_fragh(pkh_rtz(vxx[8], vxx[9]), pkh_rtz(vxx[10], vxx[11]),
                                   0u, 0u);
        __builtin_amdgcn_sched_barrier(0);   // keep X/Q MFMAs below aT consumption

        // ---- phase 4: X and Q MFMAs + pointwise ----
        f32x16 aX = MF2(wh0, bX0, zz);   f32x16 aQ = MF2(wh0, bQ0, zz);
        aX = MF2(wh1, bX1, aX);          aQ = MF2(wh1, bQ1, aQ);

        #pragma unroll
        for (int r = 0; r < 12; ++r) {
            float zx = aX[r];
            float a = vh[r], s = vs[r];
            float nx = s * zx;
            float t2 = 2.0f * a * nx;
            vx[r] = nx;
            vxx[r] = fmaf(-t2, zx, s * aQ[r]);
        }
    }

    // ---- output layer ----
    float f = 0.f, ft = 0.f, fx = 0.f, fxx = 0.f;
    #pragma unroll
    for (int r = 0; r < 12; ++r) {
        float4 t = sIn4[hi * 16 + r];
        f   = fmaf(t.w, vh[r],  f);
        ft  = fmaf(t.w, vt[r],  ft);
        fx  = fmaf(t.w, vx[r],  fx);
        fxx = fmaf(t.w, vxx[r], fxx);
    }
    f   += __shfl_xor(f, 32);
    ft  += __shfl_xor(ft, 32);
    fx  += __shfl_xor(fx, 32);
    fxx += __shfl_xor(fxx, 32);
    f += bo;

    if (!hi) {
        const float pde = 0.5f * x1 * x1 + ft + 0.5f * fxx + 0.5f * x1 * fx
                          - 0.069444444444444f * fx * fx;
        out[P] = f;
        out[NPTS + P] = pde;
    }
}

extern "C" void kernel_launch(void* const* d_in, const int* in_sizes, int n_in,
                              void* d_out, int out_size, void* d_ws, size_t ws_size,
                              hipStream_t stream) {
    const float* x     = (const float*)d_in[0];
    const float* W_in  = (const float*)d_in[1];
    const float* b_in  = (const float*)d_in[2];
    const float* W_mid = (const float*)d_in[3];
    const float* b_mid = (const float*)d_in[4];
    const float* W_out = (const float*)d_in[5];
    const float* b_out = (const float*)d_in[6];
    float* out = (float*)d_out;

    hipLaunchKernelGGL(pde_mfma_kernel, dim3(NPTS / 128), dim3(256), 0, stream,
                       x, W_in, b_in, W_mid, b_mid, W_out, b_out, out);
}

// Round 25
// 48.390 us; speedup vs baseline: 1.0947x; 1.0369x over previous
//
#include <hip/hip_runtime.h>

#define NPTS 262144
#define HID  20
#define NMID 8

typedef float f32x16 __attribute__((ext_vector_type(16)));
typedef _Float16 half8 __attribute__((ext_vector_type(8)));
typedef _Float16 half2v __attribute__((ext_vector_type(2)));
typedef __fp16 fp16x2 __attribute__((ext_vector_type(2)));
typedef unsigned int u32;

// RNE fp16 pair pack — value (H) stream (unbiased rounding for the value path).
__device__ __forceinline__ u32 pkh_rne(float a, float b) {
    half2v r; r.x = (_Float16)a; r.y = (_Float16)b;
    return __builtin_bit_cast(u32, r);
}
// RTZ fp16 pair pack (1 op, v_cvt_pkrtz_f16_f32) — derivative streams.
__device__ __forceinline__ u32 pkh_rtz(float a, float b) {
    fp16x2 r = __builtin_amdgcn_cvt_pkrtz(a, b);
    return __builtin_bit_cast(u32, r);
}

__device__ __forceinline__ half8 mk_fragh(u32 a, u32 b, u32 c, u32 d) {
    uint4 v = make_uint4(a, b, c, d);
    return __builtin_bit_cast(half8, v);
}

#define MF2(A, B, C) __builtin_amdgcn_mfma_f32_32x32x16_f16(A, B, C, 0, 0, 0)

__launch_bounds__(256, 4)
__global__ void pde_mfma_kernel(const float* __restrict__ x,
                                const float* __restrict__ W_in,
                                const float* __restrict__ b_in,
                                const float* __restrict__ W_mid,
                                const float* __restrict__ b_mid,
                                const float* __restrict__ W_out,
                                const float* __restrict__ b_out,
                                float* __restrict__ out) {
    // fp16 A-frags, hi-only weights, 2 parts/layer (16.4 KB):
    //   part0 = s=0 (64 lanes), part1 = s=1 (only lanes 0..19 nonzero; lanes
    //   32..63 correspond to k=24..31 — zero columns — zero-filled LDS).
    // Weight k-columns permuted (k -> k^12 for k in [4,12)) so B-frags equal
    // local C/D register order for both lane halves — no cross-lane ops.
    // ALL 8 MFMAs issue at layer start (no sched_barriers): MFMA-pipe latency
    // overlaps the tanh trans-chain within a wave [R24 ILP theory].
    __shared__ short sWf[NMID * 2 * 64 * 8];   // 16 KB
    __shared__ float sIn[2 * 16 * 4];

    const int tid = threadIdx.x;

    for (int idx = tid; idx < NMID * 2 * 64 * 8 / 2; idx += 256)
        ((u32*)sWf)[idx] = 0u;
    for (int idx = tid; idx < 32; idx += 256) {
        int h2i = idx >> 4, reg = idx & 15;
        int n = (reg & 3) + 8 * (reg >> 2) + 4 * h2i;
        float w0 = 0.f, w1 = 0.f, b = 0.f, wo = 0.f;
        if (n < HID) { w0 = W_in[n * 2]; w1 = W_in[n * 2 + 1]; b = b_in[n]; wo = W_out[n]; }
        sIn[idx * 4 + 0] = w0; sIn[idx * 4 + 1] = w1;
        sIn[idx * 4 + 2] = b;  sIn[idx * 4 + 3] = wo;
    }
    __syncthreads();
    // staging: per-layer outer loop -> divmod by 21 only; hi fp16 only.
    for (int layer = 0; layer < NMID; ++layer) {
        const float* Wl = W_mid + layer * HID * HID;
        const float* bl = b_mid + layer * HID;
        for (int e = tid; e < HID * (HID + 1); e += 256) {
            int j = e / (HID + 1);
            int k = e - j * (HID + 1);
            float w = (k < HID) ? Wl[j * HID + k] : bl[j];
            _Float16 whf = (_Float16)w;                       // RNE
            short whib = (short)__builtin_bit_cast(unsigned short, whf);
            int kp = (k >= 4 && k < 12) ? (k ^ 12) : k;   // column permutation
            int s = kp >> 4, kk = kp & 15, hh = kk >> 3, r = kk & 7;
            int lane = j + 32 * hh;
            sWf[((layer * 2 + s) * 64 + lane) * 8 + r] = whib;
        }
    }
    __syncthreads();

    const int lane = tid & 63;
    const int wv   = tid >> 6;
    const int p    = lane & 31;
    const int hi   = lane >> 5;
    const int P    = blockIdx.x * 128 + wv * 32 + p;

    const float2 xv = reinterpret_cast<const float2*>(x)[P];
    const float x0 = xv.x, x1 = xv.y;
    const float bo = b_out[0];

    const float4* sIn4 = reinterpret_cast<const float4*>(sIn);

    float vh[12], vs[12], vt[12], vx[12], vxx[12];

    // ---- input layer (fp32, exact) ----
    #pragma unroll
    for (int r = 0; r < 12; ++r) {
        float4 t = sIn4[hi * 16 + r];
        float z = fmaf(t.x, x0, fmaf(t.y, x1, t.z));
        float e = __expf(z + z);
        float rc = __fdividef(1.0f, e + 1.0f);
        float a = fmaf(-2.0f, rc, 1.0f);
        float s = fmaf(-a, a, 1.0f);
        float sx = s * t.y;
        vh[r] = a; vt[r] = s * t.x; vx[r] = sx;
        vxx[r] = -2.0f * a * sx * t.y;
    }

    const f32x16 zz = 0.0f;
    const half8* afp = reinterpret_cast<const half8*>(sWf);

    for (int layer = 0; layer < NMID; ++layer) {
        const int base = layer * 2 * 64;
        const half8 wh0 = afp[base + lane];
        const half8 wh1 = afp[base + 64 + lane];

        // ---- build ALL fragments from previous-layer state ----
        const half8 bH0 = mk_fragh(pkh_rne(vh[0], vh[1]), pkh_rne(vh[2], vh[3]),
                                   pkh_rne(vh[4], vh[5]), pkh_rne(vh[6], vh[7]));
        const half8 bH1 = mk_fragh(pkh_rne(vh[8], vh[9]), pkh_rne(vh[10], vh[11]),
                                   0x00003C00u, 0u);      // bias col k=20 = 1.0 fp16
        const half8 bT0 = mk_fragh(pkh_rtz(vt[0], vt[1]), pkh_rtz(vt[2], vt[3]),
                                   pkh_rtz(vt[4], vt[5]), pkh_rtz(vt[6], vt[7]));
        const half8 bT1 = mk_fragh(pkh_rtz(vt[8], vt[9]), pkh_rtz(vt[10], vt[11]),
                                   0u, 0u);
        const half8 bX0 = mk_fragh(pkh_rtz(vx[0], vx[1]), pkh_rtz(vx[2], vx[3]),
                                   pkh_rtz(vx[4], vx[5]), pkh_rtz(vx[6], vx[7]));
        const half8 bX1 = mk_fragh(pkh_rtz(vx[8], vx[9]), pkh_rtz(vx[10], vx[11]),
                                   0u, 0u);
        const half8 bQ0 = mk_fragh(pkh_rtz(vxx[0], vxx[1]), pkh_rtz(vxx[2], vxx[3]),
                                   pkh_rtz(vxx[4], vxx[5]), pkh_rtz(vxx[6], vxx[7]));
        const half8 bQ1 = mk_fragh(pkh_rtz(vxx[8], vxx[9]), pkh_rtz(vxx[10], vxx[11]),
                                   0u, 0u);

        // ---- issue all 8 MFMAs (4 independent chains) ----
        f32x16 aH = MF2(wh0, bH0, zz);
        f32x16 aT = MF2(wh0, bT0, zz);
        f32x16 aX = MF2(wh0, bX0, zz);
        f32x16 aQ = MF2(wh0, bQ0, zz);
        aH = MF2(wh1, bH1, aH);
        aT = MF2(wh1, bT1, aT);
        aX = MF2(wh1, bX1, aX);
        aQ = MF2(wh1, bQ1, aQ);

        // ---- tanh (consumes aH; overlaps with aT/aX/aQ completion) ----
        #pragma unroll
        for (int r = 0; r < 12; ++r) {
            float z = aH[r];
            float e = __expf(z + z);
            float rc = __fdividef(1.0f, e + 1.0f);
            float a = fmaf(-2.0f, rc, 1.0f);
            vh[r] = a; vs[r] = fmaf(-a, a, 1.0f);
        }

        // ---- pointwise updates ----
        #pragma unroll
        for (int r = 0; r < 12; ++r) {
            float s = vs[r];
            float zx = aX[r];
            float nx = s * zx;
            float t2 = 2.0f * vh[r] * nx;
            vt[r] = s * aT[r];
            vx[r] = nx;
            vxx[r] = fmaf(-t2, zx, s * aQ[r]);
        }
    }

    // ---- output layer ----
    float f = 0.f, ft = 0.f, fx = 0.f, fxx = 0.f;
    #pragma unroll
    for (int r = 0; r < 12; ++r) {
        float4 t = sIn4[hi * 16 + r];
        f   = fmaf(t.w, vh[r],  f);
        ft  = fmaf(t.w, vt[r],  ft);
        fx  = fmaf(t.w, vx[r],  fx);
        fxx = fmaf(t.w, vxx[r], fxx);
    }
    f   += __shfl_xor(f, 32);
    ft  += __shfl_xor(ft, 32);
    fx  += __shfl_xor(fx, 32);
    fxx += __shfl_xor(fxx, 32);
    f += bo;

    if (!hi) {
        const float pde = 0.5f * x1 * x1 + ft + 0.5f * fxx + 0.5f * x1 * fx
                          - 0.069444444444444f * fx * fx;
        out[P] = f;
        out[NPTS + P] = pde;
    }
}

extern "C" void kernel_launch(void* const* d_in, const int* in_sizes, int n_in,
                              void* d_out, int out_size, void* d_ws, size_t ws_size,
                              hipStream_t stream) {
    const float* x     = (const float*)d_in[0];
    const float* W_in  = (const float*)d_in[1];
    const float* b_in  = (const float*)d_in[2];
    const float* W_mid = (const float*)d_in[3];
    const float* b_mid = (const float*)d_in[4];
    const float* W_out = (const float*)d_in[5];
    const float* b_out = (const float*)d_in[6];
    float* out = (float*)d_out;

    hipLaunchKernelGGL(pde_mfma_kernel, dim3(NPTS / 128), dim3(256), 0, stream,
                       x, W_in, b_in, W_mid, b_mid, W_out, b_out, out);
}

// Round 26
// 48.380 us; speedup vs baseline: 1.0949x; 1.0002x over previous
//
#include <hip/hip_runtime.h>

#define NPTS 262144
#define HID  20
#define NMID 8

typedef float f32x16 __attribute__((ext_vector_type(16)));
typedef _Float16 half8 __attribute__((ext_vector_type(8)));
typedef __fp16 fp16x2 __attribute__((ext_vector_type(2)));
typedef unsigned int u32;

// RTZ fp16 pair pack (1 op, v_cvt_pkrtz_f16_f32) — all streams.
// fp16-RTZ bias = 2^-12/layer (8x below R15's failed bf16 case; R20 proved
// H-RTZ passes at absmax 0.039).
__device__ __forceinline__ u32 pkh_rtz(float a, float b) {
    fp16x2 r = __builtin_amdgcn_cvt_pkrtz(a, b);
    return __builtin_bit_cast(u32, r);
}

__device__ __forceinline__ half8 mk_fragh(u32 a, u32 b, u32 c, u32 d) {
    uint4 v = make_uint4(a, b, c, d);
    return __builtin_bit_cast(half8, v);
}

#define MF2(A, B, C) __builtin_amdgcn_mfma_f32_32x32x16_f16(A, B, C, 0, 0, 0)

__launch_bounds__(256, 4)
__global__ void pde_mfma_kernel(const float* __restrict__ x,
                                const float* __restrict__ W_in,
                                const float* __restrict__ b_in,
                                const float* __restrict__ W_mid,
                                const float* __restrict__ b_mid,
                                const float* __restrict__ W_out,
                                const float* __restrict__ b_out,
                                float* __restrict__ out) {
    // fp16 A-frags, hi-only weights SCALED BY 2 (exact: exponent bump only),
    // 2 parts/layer (16.4 KB). part1 lanes 32..63 = k=24..31 zero columns.
    // Weight k-columns permuted (k -> k^12 for k in [4,12)) so B-frags equal
    // local C/D register order for both lane halves — no cross-lane ops.
    // MFMA outputs are 2x true: exp(2z) needs no doubling; s2 = s/2 absorbs
    // the rest (all state arrays hold TRUE values) [R25 theory].
    __shared__ short sWf[NMID * 2 * 64 * 8];   // 16 KB
    __shared__ float sIn[2 * 16 * 4];

    const int tid = threadIdx.x;

    for (int idx = tid; idx < NMID * 2 * 64 * 8 / 2; idx += 256)
        ((u32*)sWf)[idx] = 0u;
    for (int idx = tid; idx < 32; idx += 256) {
        int h2i = idx >> 4, reg = idx & 15;
        int n = (reg & 3) + 8 * (reg >> 2) + 4 * h2i;
        float w0 = 0.f, w1 = 0.f, b = 0.f, wo = 0.f;
        if (n < HID) {
            w0 = 2.0f * W_in[n * 2];      // scaled-by-2 (exact)
            w1 = 2.0f * W_in[n * 2 + 1];
            b  = 2.0f * b_in[n];
            wo = W_out[n];                 // output weights unscaled
        }
        sIn[idx * 4 + 0] = w0; sIn[idx * 4 + 1] = w1;
        sIn[idx * 4 + 2] = b;  sIn[idx * 4 + 3] = wo;
    }
    __syncthreads();
    // staging: per-layer outer loop; weights*2, hi fp16 only.
    for (int layer = 0; layer < NMID; ++layer) {
        const float* Wl = W_mid + layer * HID * HID;
        const float* bl = b_mid + layer * HID;
        for (int e = tid; e < HID * (HID + 1); e += 256) {
            int j = e / (HID + 1);
            int k = e - j * (HID + 1);
            float w = 2.0f * ((k < HID) ? Wl[j * HID + k] : bl[j]);
            _Float16 whf = (_Float16)w;                       // RNE
            short whib = (short)__builtin_bit_cast(unsigned short, whf);
            int kp = (k >= 4 && k < 12) ? (k ^ 12) : k;   // column permutation
            int s = kp >> 4, kk = kp & 15, hh = kk >> 3, r = kk & 7;
            int lane = j + 32 * hh;
            sWf[((layer * 2 + s) * 64 + lane) * 8 + r] = whib;
        }
    }
    __syncthreads();

    const int lane = tid & 63;
    const int wv   = tid >> 6;
    const int p    = lane & 31;
    const int hi   = lane >> 5;
    const int P    = blockIdx.x * 128 + wv * 32 + p;

    const float2 xv = reinterpret_cast<const float2*>(x)[P];
    const float x0 = xv.x, x1 = xv.y;
    const float bo = b_out[0];

    const float4* sIn4 = reinterpret_cast<const float4*>(sIn);

    // state: TRUE values. vs holds s2 = (1 - a^2)/2.
    float vh[12], vs[12], vt[12], vx[12], vxx[12];

    // ---- input layer (fp32; sIn pre-scaled by 2) ----
    #pragma unroll
    for (int r = 0; r < 12; ++r) {
        float4 t = sIn4[hi * 16 + r];              // t.x=2w0, t.y=2w1, t.z=2b
        float z2 = fmaf(t.x, x0, fmaf(t.y, x1, t.z));   // = 2z
        float e = __expf(z2);
        float rc = __fdividef(1.0f, e + 1.0f);
        float a = fmaf(-2.0f, rc, 1.0f);
        float u = -0.5f * a;
        float s2 = fmaf(u, a, 0.5f);               // (1-a^2)/2
        float sx = s2 * t.y;                       // = s*w1 (true)
        vh[r] = a; vs[r] = s2; vt[r] = s2 * t.x;   // = s*w0 (true)
        vx[r] = sx;
        vxx[r] = -(a * sx) * t.y;                  // = -2a*s*w1^2 (true)
    }

    const f32x16 zz = 0.0f;
    const half8* afp = reinterpret_cast<const half8*>(sWf);

    for (int layer = 0; layer < NMID; ++layer) {
        const int base = layer * 2 * 64;
        const half8 wh0 = afp[base + lane];
        const half8 wh1 = afp[base + 64 + lane];

        // ---- build ALL fragments from previous-layer TRUE state ----
        const half8 bH0 = mk_fragh(pkh_rtz(vh[0], vh[1]), pkh_rtz(vh[2], vh[3]),
                                   pkh_rtz(vh[4], vh[5]), pkh_rtz(vh[6], vh[7]));
        const half8 bH1 = mk_fragh(pkh_rtz(vh[8], vh[9]), pkh_rtz(vh[10], vh[11]),
                                   0x00003C00u, 0u);      // bias col k=20 = 1.0
        const half8 bT0 = mk_fragh(pkh_rtz(vt[0], vt[1]), pkh_rtz(vt[2], vt[3]),
                                   pkh_rtz(vt[4], vt[5]), pkh_rtz(vt[6], vt[7]));
        const half8 bT1 = mk_fragh(pkh_rtz(vt[8], vt[9]), pkh_rtz(vt[10], vt[11]),
                                   0u, 0u);
        const half8 bX0 = mk_fragh(pkh_rtz(vx[0], vx[1]), pkh_rtz(vx[2], vx[3]),
                                   pkh_rtz(vx[4], vx[5]), pkh_rtz(vx[6], vx[7]));
        const half8 bX1 = mk_fragh(pkh_rtz(vx[8], vx[9]), pkh_rtz(vx[10], vx[11]),
                                   0u, 0u);
        const half8 bQ0 = mk_fragh(pkh_rtz(vxx[0], vxx[1]), pkh_rtz(vxx[2], vxx[3]),
                                   pkh_rtz(vxx[4], vxx[5]), pkh_rtz(vxx[6], vxx[7]));
        const half8 bQ1 = mk_fragh(pkh_rtz(vxx[8], vxx[9]), pkh_rtz(vxx[10], vxx[11]),
                                   0u, 0u);

        // ---- issue all 8 MFMAs (outputs = 2x true z/zt/zx/zq) ----
        f32x16 aH = MF2(wh0, bH0, zz);
        f32x16 aT = MF2(wh0, bT0, zz);
        f32x16 aX = MF2(wh0, bX0, zz);
        f32x16 aQ = MF2(wh0, bQ0, zz);
        aH = MF2(wh1, bH1, aH);
        aT = MF2(wh1, bT1, aT);
        aX = MF2(wh1, bX1, aX);
        aQ = MF2(wh1, bQ1, aQ);

        // ---- tanh: aH = 2z, so exp(aH) directly ----
        #pragma unroll
        for (int r = 0; r < 12; ++r) {
            float e = __expf(aH[r]);
            float rc = __fdividef(1.0f, e + 1.0f);
            float a = fmaf(-2.0f, rc, 1.0f);
            float u = -0.5f * a;
            vh[r] = a; vs[r] = fmaf(u, a, 0.5f);   // s2
        }

        // ---- pointwise (scaled-aware; state stays TRUE) ----
        #pragma unroll
        for (int r = 0; r < 12; ++r) {
            float s2 = vs[r];
            float nx = s2 * aX[r];                 // = s*zx (true)
            float u2 = vh[r] * nx;                 // a*nx
            float w  = u2 * aX[r];                 // a*nx*2zx = 2a*s*zx^2
            vt[r] = s2 * aT[r];                    // = s*zt (true)
            vx[r] = nx;
            vxx[r] = fmaf(s2, aQ[r], -w);          // = s*zq - 2a*s*zx^2 (true)
        }
    }

    // ---- output layer ----
    float f = 0.f, ft = 0.f, fx = 0.f, fxx = 0.f;
    #pragma unroll
    for (int r = 0; r < 12; ++r) {
        float4 t = sIn4[hi * 16 + r];
        f   = fmaf(t.w, vh[r],  f);
        ft  = fmaf(t.w, vt[r],  ft);
        fx  = fmaf(t.w, vx[r],  fx);
        fxx = fmaf(t.w, vxx[r], fxx);
    }
    f   += __shfl_xor(f, 32);
    ft  += __shfl_xor(ft, 32);
    fx  += __shfl_xor(fx, 32);
    fxx += __shfl_xor(fxx, 32);
    f += bo;

    if (!hi) {
        const float pde = 0.5f * x1 * x1 + ft + 0.5f * fxx + 0.5f * x1 * fx
                          - 0.069444444444444f * fx * fx;
        out[P] = f;
        out[NPTS + P] = pde;
    }
}

extern "C" void kernel_launch(void* const* d_in, const int* in_sizes, int n_in,
                              void* d_out, int out_size, void* d_ws, size_t ws_size,
                              hipStream_t stream) {
    const float* x     = (const float*)d_in[0];
    const float* W_in  = (const float*)d_in[1];
    const float* b_in  = (const float*)d_in[2];
    const float* W_mid = (const float*)d_in[3];
    const float* b_mid = (const float*)d_in[4];
    const float* W_out = (const float*)d_in[5];
    const float* b_out = (const float*)d_in[6];
    float* out = (float*)d_out;

    hipLaunchKernelGGL(pde_mfma_kernel, dim3(NPTS / 128), dim3(256), 0, stream,
                       x, W_in, b_in, W_mid, b_mid, W_out, b_out, out);
}